// Round 1
// baseline (321.495 us; speedup 1.0000x reference)
//
#include <hip/hip_runtime.h>
#include <stdint.h>

typedef __bf16 bf16_t;
typedef __bf16 bf16x8 __attribute__((ext_vector_type(8)));
typedef float f32x4 __attribute__((ext_vector_type(4)));

__device__ __forceinline__ f32x4 mfma16(bf16x8 a, bf16x8 b, f32x4 c) {
  return __builtin_amdgcn_mfma_f32_16x16x32_bf16(a, b, c, 0, 0, 0);
}

__device__ __forceinline__ void g2l16(const void* g, void* l) {
  __builtin_amdgcn_global_load_lds((const __attribute__((address_space(1))) void*)g,
                                   (__attribute__((address_space(3))) void*)l, 16, 0, 0);
}

// ---------------- f32 -> bf16 convert (vectorized, exact grid) ----------------
__global__ void __launch_bounds__(256) cvt_f32_bf16(const float* __restrict__ in,
                                                    bf16_t* __restrict__ out) {
  long i = ((long)blockIdx.x * 256 + threadIdx.x) * 8;
  float4 f0 = *(const float4*)(in + i);
  float4 f1 = *(const float4*)(in + i + 4);
  bf16x8 v;
  v[0] = (bf16_t)f0.x; v[1] = (bf16_t)f0.y; v[2] = (bf16_t)f0.z; v[3] = (bf16_t)f0.w;
  v[4] = (bf16_t)f1.x; v[5] = (bf16_t)f1.y; v[6] = (bf16_t)f1.z; v[7] = (bf16_t)f1.w;
  *(bf16x8*)(out + i) = v;
}

// ---------------- m97-style GEMM: C[M,N] = A[M,K] * Bt[N,K]^T ----------------
// A, Bt bf16 row-major; OutT = bf16 or float. 128x128 tile, BK=32, 256 threads.
template <typename OutT>
__global__ void __launch_bounds__(256) gemm_bt(const bf16_t* __restrict__ A,
                                               const bf16_t* __restrict__ Bt,
                                               OutT* __restrict__ C,
                                               int M, int N, int K) {
  __shared__ bf16_t As[128 * 32];
  __shared__ bf16_t Bs[128 * 32];
  const int t = threadIdx.x;
  const int w = t >> 6, l = t & 63;
  const int lr = l & 15, lg = l >> 4;
  const int wm = (w >> 1) * 64, wn = (w & 1) * 64;
  const long bm = blockIdx.x, bn = blockIdx.y;

  // staging map: call c covers tile rows [c*64, c*64+64); row = c*64 + w*16 + l/4
  const int srow = w * 16 + (l >> 2);
  const int scol = (l & 3) * 8;
  const bf16_t* gA = A + (bm * 128 + srow) * (long)K + scol;
  const bf16_t* gB = Bt + (bn * 128 + srow) * (long)K + scol;
  bf16_t* lA = As + w * 512 + l * 8;  // wave-uniform base + lane*16B
  bf16_t* lB = Bs + w * 512 + l * 8;

  f32x4 acc[4][4] = {};
  for (int kt = 0; kt < K; kt += 32) {
    g2l16(gA + kt, lA);
    g2l16(gA + 64 * (long)K + kt, lA + 2048);
    g2l16(gB + kt, lB);
    g2l16(gB + 64 * (long)K + kt, lB + 2048);
    __syncthreads();
    bf16x8 a[4], b[4];
#pragma unroll
    for (int i = 0; i < 4; ++i) a[i] = *(const bf16x8*)&As[(wm + i * 16 + lr) * 32 + lg * 8];
#pragma unroll
    for (int i = 0; i < 4; ++i) b[i] = *(const bf16x8*)&Bs[(wn + i * 16 + lr) * 32 + lg * 8];
#pragma unroll
    for (int i = 0; i < 4; ++i)
#pragma unroll
      for (int j = 0; j < 4; ++j) acc[i][j] = mfma16(a[i], b[j], acc[i][j]);
    __syncthreads();
  }
#pragma unroll
  for (int i = 0; i < 4; ++i)
#pragma unroll
    for (int j = 0; j < 4; ++j)
#pragma unroll
      for (int r = 0; r < 4; ++r) {
        long row = bm * 128 + wm + i * 16 + lg * 4 + r;
        long col = bn * 128 + wn + j * 16 + lr;
        C[row * (long)N + col] = (OutT)acc[i][j][r];
      }
}

// ---------------- sliding-window attention ----------------
// QKV: [16384, 3072] bf16 (cols: Q 0..1023, K 1024..2047, V 2048..3071; feature = h*64+d)
// one block per (b, h, window n); 4 waves, each owns 32 q-rows; flash over <=3 K-chunks.
__global__ void __launch_bounds__(256) swa_kernel(const bf16_t* __restrict__ QKV,
                                                  const float* __restrict__ amask,
                                                  bf16_t* __restrict__ Att) {
  __shared__ bf16_t Vs[64 * 136];       // V^T, padded (row stride 272B)
  __shared__ bf16_t Ps[4 * 32 * 136];   // per-wave P, padded
  __shared__ float bias[128];

  const int idx = blockIdx.x;
  const int n = idx & 31;
  const int h = (idx >> 5) & 15;
  const int b = idx >> 9;
  const int t = threadIdx.x;
  const int w = t >> 6;
  const int l = t & 63;
  const int lr = l & 15;
  const int lg = l >> 4;

  const long rowQ = (long)b * 4096 + n * 128;

  // Q fragments in registers (A-operand layout: row = lr, k = lg*8..+8)
  bf16x8 qf[2][2];
#pragma unroll
  for (int mi = 0; mi < 2; ++mi)
#pragma unroll
    for (int ks = 0; ks < 2; ++ks)
      qf[mi][ks] = *(const bf16x8*)&QKV[(rowQ + w * 32 + mi * 16 + lr) * 3072 + h * 64 + ks * 32 + lg * 8];

  f32x4 o[2][4] = {};
  f32x4 m_run[2], l_run[2];
#pragma unroll
  for (int mi = 0; mi < 2; ++mi)
#pragma unroll
    for (int r = 0; r < 4; ++r) { m_run[mi][r] = -1e30f; l_run[mi][r] = 0.f; }

  const int kcLo = (n > 0) ? n - 1 : 0;
  const int kcHi = (n < 31) ? n + 1 : 31;
  for (int kc = kcLo; kc <= kcHi; ++kc) {
    const long kbase = (long)b * 4096 + (long)kc * 128;
    __syncthreads();  // previous chunk's Vs/Ps reads complete
    // stage V transposed: Vs[d][k]
#pragma unroll
    for (int c = 0; c < 4; ++c) {
      int id = c * 256 + t;
      int kloc = id >> 3;
      int d0 = (id & 7) * 8;
      bf16x8 v = *(const bf16x8*)&QKV[(kbase + kloc) * 3072 + 2048 + h * 64 + d0];
#pragma unroll
      for (int j = 0; j < 8; ++j) Vs[(d0 + j) * 136 + kloc] = v[j];
    }
    if (t < 128) bias[t] = (amask[kbase + t] > 0.f) ? 0.f : -1e30f;
    __syncthreads();

    // QK^T : S[q, key] ; K fragments direct from global (L2-resident)
    f32x4 s[2][8] = {};
    const bf16_t* Kb = QKV + kbase * 3072 + 1024 + h * 64;
#pragma unroll
    for (int nf = 0; nf < 8; ++nf) {
#pragma unroll
      for (int ks = 0; ks < 2; ++ks) {
        bf16x8 kf = *(const bf16x8*)&Kb[(nf * 16 + lr) * 3072 + ks * 32 + lg * 8];
        s[0][nf] = mfma16(qf[0][ks], kf, s[0][nf]);
        s[1][nf] = mfma16(qf[1][ks], kf, s[1][nf]);
      }
    }

    // online softmax per 16-row fragment group (rows live in 16-lane groups)
#pragma unroll
    for (int mi = 0; mi < 2; ++mi) {
      f32x4 rm;
#pragma unroll
      for (int r = 0; r < 4; ++r) rm[r] = -3e30f;
#pragma unroll
      for (int nf = 0; nf < 8; ++nf) {
        float bv = bias[nf * 16 + lr];
#pragma unroll
        for (int r = 0; r < 4; ++r) {
          float sv = s[mi][nf][r] * 0.125f + bv;
          s[mi][nf][r] = sv;
          rm[r] = fmaxf(rm[r], sv);
        }
      }
#pragma unroll
      for (int off = 8; off > 0; off >>= 1)
#pragma unroll
        for (int r = 0; r < 4; ++r) rm[r] = fmaxf(rm[r], __shfl_xor(rm[r], off));
      f32x4 mnew, alpha, rs;
#pragma unroll
      for (int r = 0; r < 4; ++r) {
        mnew[r] = fmaxf(m_run[mi][r], rm[r]);
        alpha[r] = __expf(m_run[mi][r] - mnew[r]);
        m_run[mi][r] = mnew[r];
        rs[r] = 0.f;
      }
#pragma unroll
      for (int nf = 0; nf < 8; ++nf)
#pragma unroll
        for (int r = 0; r < 4; ++r) {
          float p = __expf(s[mi][nf][r] - mnew[r]);
          s[mi][nf][r] = p;
          rs[r] += p;
        }
#pragma unroll
      for (int off = 8; off > 0; off >>= 1)
#pragma unroll
        for (int r = 0; r < 4; ++r) rs[r] += __shfl_xor(rs[r], off);
#pragma unroll
      for (int r = 0; r < 4; ++r) l_run[mi][r] = l_run[mi][r] * alpha[r] + rs[r];
#pragma unroll
      for (int nf = 0; nf < 4; ++nf)
#pragma unroll
        for (int r = 0; r < 4; ++r) o[mi][nf][r] *= alpha[r];
      // P (D-layout) -> LDS for re-fragmenting as A-operand
#pragma unroll
      for (int nf = 0; nf < 8; ++nf)
#pragma unroll
        for (int r = 0; r < 4; ++r)
          Ps[(w * 32 + mi * 16 + lg * 4 + r) * 136 + nf * 16 + lr] = (bf16_t)s[mi][nf][r];
    }
    __syncthreads();

    // PV: O[q,d] += P[q,k] * V[k,d]
#pragma unroll
    for (int ks = 0; ks < 4; ++ks) {
      bf16x8 pa0 = *(const bf16x8*)&Ps[(w * 32 + lr) * 136 + ks * 32 + lg * 8];
      bf16x8 pa1 = *(const bf16x8*)&Ps[(w * 32 + 16 + lr) * 136 + ks * 32 + lg * 8];
#pragma unroll
      for (int nf = 0; nf < 4; ++nf) {
        bf16x8 vf = *(const bf16x8*)&Vs[(nf * 16 + lr) * 136 + ks * 32 + lg * 8];
        o[0][nf] = mfma16(pa0, vf, o[0][nf]);
        o[1][nf] = mfma16(pa1, vf, o[1][nf]);
      }
    }
  }

  // epilogue: normalize and store attended (bf16), layout [16384, 1024], col = h*64+d
#pragma unroll
  for (int mi = 0; mi < 2; ++mi) {
    f32x4 inv;
#pragma unroll
    for (int r = 0; r < 4; ++r) inv[r] = 1.0f / l_run[mi][r];
#pragma unroll
    for (int nf = 0; nf < 4; ++nf)
#pragma unroll
      for (int r = 0; r < 4; ++r) {
        long row = rowQ + w * 32 + mi * 16 + lg * 4 + r;
        int col = h * 64 + nf * 16 + lr;
        Att[row * 1024 + col] = (bf16_t)(o[mi][nf][r] * inv[r]);
      }
  }
}

// ---------------- launch ----------------
extern "C" void kernel_launch(void* const* d_in, const int* in_sizes, int n_in,
                              void* d_out, int out_size, void* d_ws, size_t ws_size,
                              hipStream_t stream) {
  const float* x  = (const float*)d_in[0];
  const float* am = (const float*)d_in[1];
  const float* Wq = (const float*)d_in[2];
  const float* Wk = (const float*)d_in[3];
  const float* Wv = (const float*)d_in[4];
  const float* Wo = (const float*)d_in[5];
  float* out = (float*)d_out;

  char* ws = (char*)d_ws;
  bf16_t* qkv  = (bf16_t*)ws;                       // 16384*3072 bf16 = 100663296 B
  bf16_t* xb   = (bf16_t*)(ws + 100663296);         // 16384*1024 bf16 (reused as attended)
  bf16_t* wqkv = (bf16_t*)(ws + 134217728);         // 3072*1024 bf16 (rows: Wq,Wk,Wv)
  bf16_t* wob  = (bf16_t*)(ws + 140509184);         // 1024*1024 bf16

  // converts (exact grids; n divisible by 2048)
  cvt_f32_bf16<<<8192, 256, 0, stream>>>(x, xb);                    // 16.78M elems
  cvt_f32_bf16<<<512, 256, 0, stream>>>(Wq, wqkv);
  cvt_f32_bf16<<<512, 256, 0, stream>>>(Wk, wqkv + 1048576);
  cvt_f32_bf16<<<512, 256, 0, stream>>>(Wv, wqkv + 2097152);
  cvt_f32_bf16<<<512, 256, 0, stream>>>(Wo, wob);

  // QKV projection: [16384,1024] x [3072,1024]^T -> [16384,3072] bf16
  dim3 g1(128, 24);
  gemm_bt<bf16_t><<<g1, 256, 0, stream>>>(xb, wqkv, qkv, 16384, 3072, 1024);

  // local attention -> attended [16384,1024] bf16 (overwrites xb region)
  swa_kernel<<<2048, 256, 0, stream>>>(qkv, am, xb);

  // output projection: [16384,1024] x [1024,1024]^T -> d_out f32
  dim3 g2(128, 8);
  gemm_bt<float><<<g2, 256, 0, stream>>>(xb, wob, out, 16384, 1024, 1024);
}

// Round 2
// 302.534 us; speedup vs baseline: 1.0627x; 1.0627x over previous
//
#include <hip/hip_runtime.h>
#include <stdint.h>

typedef __bf16 bf16_t;
typedef __bf16 bf16x8 __attribute__((ext_vector_type(8)));
typedef float f32x4 __attribute__((ext_vector_type(4)));

__device__ __forceinline__ f32x4 mfma16(bf16x8 a, bf16x8 b, f32x4 c) {
  return __builtin_amdgcn_mfma_f32_16x16x32_bf16(a, b, c, 0, 0, 0);
}

__device__ __forceinline__ void g2l16(const void* g, void* l) {
  __builtin_amdgcn_global_load_lds((const __attribute__((address_space(1))) void*)g,
                                   (__attribute__((address_space(3))) void*)l, 16, 0, 0);
}

#define FENCE() asm volatile("" ::: "memory")

// ---------------- f32 -> bf16 convert (vectorized, exact grid) ----------------
__global__ void __launch_bounds__(256) cvt_f32_bf16(const float* __restrict__ in,
                                                    bf16_t* __restrict__ out) {
  long i = ((long)blockIdx.x * 256 + threadIdx.x) * 8;
  float4 f0 = *(const float4*)(in + i);
  float4 f1 = *(const float4*)(in + i + 4);
  bf16x8 v;
  v[0] = (bf16_t)f0.x; v[1] = (bf16_t)f0.y; v[2] = (bf16_t)f0.z; v[3] = (bf16_t)f0.w;
  v[4] = (bf16_t)f1.x; v[5] = (bf16_t)f1.y; v[6] = (bf16_t)f1.z; v[7] = (bf16_t)f1.w;
  *(bf16x8*)(out + i) = v;
}

// ---------------- phase-split GEMM: C[M,N] = A[M,K] * Bt[N,K]^T ----------------
// BM=256, BN=128, BK=64. 512 threads = 8 waves (4M x 2N), per-wave C 64x64.
// 3-slot LDS ring (48KB/slot: A 32KB + B 16KB), XOR-swizzled layout:
//   element(row, col16) at byte row*128 + ((col16 ^ (row&7))*16)  [col16 = 16B group]
// Staging pre-swizzles the GLOBAL source so global_load_lds' linear dest lands swizzled.
// 2 phases / K-tile; counted vmcnt(6) at tile end (never drains in steady state).
template <typename OutT>
__global__ void __launch_bounds__(512, 2) gemm8p(const bf16_t* __restrict__ A,
                                                 const bf16_t* __restrict__ Bt,
                                                 OutT* __restrict__ C,
                                                 int M, int N, int K) {
  extern __shared__ char smem[];
  const int t = threadIdx.x;
  const int w = t >> 6, l = t & 63;
  const int lr = l & 15, lg = l >> 4;
  const int wm = w >> 1, wn = w & 1;
  const long rowA0 = (long)blockIdx.x * 256;
  const long rowB0 = (long)blockIdx.y * 128;
  const int KT = K >> 6;

  // staging map: per seg (8KB) a wave writes rows [seg*64 + w*8, +8), lane lands at
  // slot (l&7) of row (.. + l>>3); logical col16 = (l&7)^(l>>3)  (the involution)
  const int rowStage = w * 8 + (l >> 3);
  const int colSwz = ((l & 7) ^ (l >> 3)) * 8;  // elements
  const bf16_t* gA = A + (rowA0 + rowStage) * (long)K + colSwz;
  const bf16_t* gB = Bt + (rowB0 + rowStage) * (long)K + colSwz;
  const long K64 = (long)K * 64;

  // fragment-read swizzled 16B-slot offsets (row&7 == lr&7 for all frag rows)
  const int sx0 = ((lg) ^ (lr & 7)) * 16;
  const int sx1 = ((4 + lg) ^ (lr & 7)) * 16;
  const int aOff = (wm * 64 + lr) * 128;
  const int bOff = 32768 + (wn * 64 + lr) * 128;

  f32x4 acc[4][4] = {};

#define STAGE_H0(slot, kt)                                              \
  {                                                                     \
    char* _b = smem + (slot) * 49152 + w * 1024;                        \
    const long _ko = (long)(kt) * 64;                                   \
    g2l16(gA + _ko, _b);                   /* A rows   0.. 63 */        \
    g2l16(gA + K64 + _ko, _b + 8192);      /* A rows  64..127 */        \
    g2l16(gB + _ko, _b + 32768);           /* B rows   0.. 63 */        \
  }
#define STAGE_H1(slot, kt)                                              \
  {                                                                     \
    char* _b = smem + (slot) * 49152 + w * 1024;                        \
    const long _ko = (long)(kt) * 64;                                   \
    g2l16(gA + 2 * K64 + _ko, _b + 16384); /* A rows 128..191 */        \
    g2l16(gA + 3 * K64 + _ko, _b + 24576); /* A rows 192..255 */        \
    g2l16(gB + K64 + _ko, _b + 40960);     /* B rows  64..127 */        \
  }

  // prologue: tiles 0 and 1 into slots 0,1; wait tile 0 (6 loads remain in flight)
  STAGE_H0(0, 0); STAGE_H1(0, 0);
  STAGE_H0(1, 1); STAGE_H1(1, 1);
  FENCE();
  asm volatile("s_waitcnt vmcnt(6)" ::: "memory");
  __builtin_amdgcn_s_barrier();

  for (int kt2 = 0; kt2 < KT; ++kt2) {
    const int slot = kt2 % 3;
    const int nslot = (kt2 + 2) % 3;
    const bool doStage = (kt2 + 2) < KT;
    const char* sb = smem + slot * 49152;

    // ---- phase 0: B all 8 frags + A rows 0,1 (12 ds_read_b128) ----
    bf16x8 bfr[4][2], a01[2][2];
#pragma unroll
    for (int j = 0; j < 4; ++j) {
      bfr[j][0] = *(const bf16x8*)(sb + bOff + j * 2048 + sx0);
      bfr[j][1] = *(const bf16x8*)(sb + bOff + j * 2048 + sx1);
    }
#pragma unroll
    for (int i = 0; i < 2; ++i) {
      a01[i][0] = *(const bf16x8*)(sb + aOff + i * 2048 + sx0);
      a01[i][1] = *(const bf16x8*)(sb + aOff + i * 2048 + sx1);
    }
    if (doStage) STAGE_H0(nslot, kt2 + 2);
    FENCE();
    __builtin_amdgcn_s_barrier();
    asm volatile("s_waitcnt lgkmcnt(0)" ::: "memory");
    __builtin_amdgcn_sched_barrier(0);
    __builtin_amdgcn_s_setprio(1);
#pragma unroll
    for (int i = 0; i < 2; ++i)
#pragma unroll
      for (int j = 0; j < 4; ++j) {
        acc[i][j] = mfma16(a01[i][0], bfr[j][0], acc[i][j]);
        acc[i][j] = mfma16(a01[i][1], bfr[j][1], acc[i][j]);
      }
    __builtin_amdgcn_s_setprio(0);
    __builtin_amdgcn_sched_barrier(0);
    FENCE();
    __builtin_amdgcn_s_barrier();

    // ---- phase 1: A rows 2,3 (4 ds_read_b128) ----
    bf16x8 a23[2][2];
#pragma unroll
    for (int i = 0; i < 2; ++i) {
      a23[i][0] = *(const bf16x8*)(sb + aOff + (i + 2) * 2048 + sx0);
      a23[i][1] = *(const bf16x8*)(sb + aOff + (i + 2) * 2048 + sx1);
    }
    if (doStage) STAGE_H1(nslot, kt2 + 2);
    FENCE();
    __builtin_amdgcn_s_barrier();
    asm volatile("s_waitcnt lgkmcnt(0)" ::: "memory");
    __builtin_amdgcn_sched_barrier(0);
    __builtin_amdgcn_s_setprio(1);
#pragma unroll
    for (int i = 0; i < 2; ++i)
#pragma unroll
      for (int j = 0; j < 4; ++j) {
        acc[i + 2][j] = mfma16(a23[i][0], bfr[j][0], acc[i + 2][j]);
        acc[i + 2][j] = mfma16(a23[i][1], bfr[j][1], acc[i + 2][j]);
      }
    __builtin_amdgcn_s_setprio(0);
    __builtin_amdgcn_sched_barrier(0);
    FENCE();
    // tile boundary: ensure tile kt2+1 complete; keep kt2+2's 6 loads in flight
    if (doStage) {
      asm volatile("s_waitcnt vmcnt(6)" ::: "memory");
    } else if (kt2 + 1 < KT) {
      asm volatile("s_waitcnt vmcnt(0)" ::: "memory");
    }
    __builtin_amdgcn_s_barrier();
  }

  // epilogue
#pragma unroll
  for (int i = 0; i < 4; ++i)
#pragma unroll
    for (int j = 0; j < 4; ++j)
#pragma unroll
      for (int r = 0; r < 4; ++r) {
        long row = rowA0 + wm * 64 + i * 16 + lg * 4 + r;
        long col = rowB0 + wn * 64 + j * 16 + lr;
        C[row * (long)N + col] = (OutT)acc[i][j][r];
      }
#undef STAGE_H0
#undef STAGE_H1
}

// ---------------- sliding-window attention (unchanged from round 1) ----------------
__global__ void __launch_bounds__(256) swa_kernel(const bf16_t* __restrict__ QKV,
                                                  const float* __restrict__ amask,
                                                  bf16_t* __restrict__ Att) {
  __shared__ bf16_t Vs[64 * 136];       // V^T, padded (row stride 272B)
  __shared__ bf16_t Ps[4 * 32 * 136];   // per-wave P, padded
  __shared__ float bias[128];

  const int idx = blockIdx.x;
  const int n = idx & 31;
  const int h = (idx >> 5) & 15;
  const int b = idx >> 9;
  const int t = threadIdx.x;
  const int w = t >> 6;
  const int l = t & 63;
  const int lr = l & 15;
  const int lg = l >> 4;

  const long rowQ = (long)b * 4096 + n * 128;

  bf16x8 qf[2][2];
#pragma unroll
  for (int mi = 0; mi < 2; ++mi)
#pragma unroll
    for (int ks = 0; ks < 2; ++ks)
      qf[mi][ks] = *(const bf16x8*)&QKV[(rowQ + w * 32 + mi * 16 + lr) * 3072 + h * 64 + ks * 32 + lg * 8];

  f32x4 o[2][4] = {};
  f32x4 m_run[2], l_run[2];
#pragma unroll
  for (int mi = 0; mi < 2; ++mi)
#pragma unroll
    for (int r = 0; r < 4; ++r) { m_run[mi][r] = -1e30f; l_run[mi][r] = 0.f; }

  const int kcLo = (n > 0) ? n - 1 : 0;
  const int kcHi = (n < 31) ? n + 1 : 31;
  for (int kc = kcLo; kc <= kcHi; ++kc) {
    const long kbase = (long)b * 4096 + (long)kc * 128;
    __syncthreads();
#pragma unroll
    for (int c = 0; c < 4; ++c) {
      int id = c * 256 + t;
      int kloc = id >> 3;
      int d0 = (id & 7) * 8;
      bf16x8 v = *(const bf16x8*)&QKV[(kbase + kloc) * 3072 + 2048 + h * 64 + d0];
#pragma unroll
      for (int j = 0; j < 8; ++j) Vs[(d0 + j) * 136 + kloc] = v[j];
    }
    if (t < 128) bias[t] = (amask[kbase + t] > 0.f) ? 0.f : -1e30f;
    __syncthreads();

    f32x4 s[2][8] = {};
    const bf16_t* Kb = QKV + kbase * 3072 + 1024 + h * 64;
#pragma unroll
    for (int nf = 0; nf < 8; ++nf) {
#pragma unroll
      for (int ks = 0; ks < 2; ++ks) {
        bf16x8 kf = *(const bf16x8*)&Kb[(nf * 16 + lr) * 3072 + ks * 32 + lg * 8];
        s[0][nf] = mfma16(qf[0][ks], kf, s[0][nf]);
        s[1][nf] = mfma16(qf[1][ks], kf, s[1][nf]);
      }
    }

#pragma unroll
    for (int mi = 0; mi < 2; ++mi) {
      f32x4 rm;
#pragma unroll
      for (int r = 0; r < 4; ++r) rm[r] = -3e30f;
#pragma unroll
      for (int nf = 0; nf < 8; ++nf) {
        float bv = bias[nf * 16 + lr];
#pragma unroll
        for (int r = 0; r < 4; ++r) {
          float sv = s[mi][nf][r] * 0.125f + bv;
          s[mi][nf][r] = sv;
          rm[r] = fmaxf(rm[r], sv);
        }
      }
#pragma unroll
      for (int off = 8; off > 0; off >>= 1)
#pragma unroll
        for (int r = 0; r < 4; ++r) rm[r] = fmaxf(rm[r], __shfl_xor(rm[r], off));
      f32x4 mnew, alpha, rs;
#pragma unroll
      for (int r = 0; r < 4; ++r) {
        mnew[r] = fmaxf(m_run[mi][r], rm[r]);
        alpha[r] = __expf(m_run[mi][r] - mnew[r]);
        m_run[mi][r] = mnew[r];
        rs[r] = 0.f;
      }
#pragma unroll
      for (int nf = 0; nf < 8; ++nf)
#pragma unroll
        for (int r = 0; r < 4; ++r) {
          float p = __expf(s[mi][nf][r] - mnew[r]);
          s[mi][nf][r] = p;
          rs[r] += p;
        }
#pragma unroll
      for (int off = 8; off > 0; off >>= 1)
#pragma unroll
        for (int r = 0; r < 4; ++r) rs[r] += __shfl_xor(rs[r], off);
#pragma unroll
      for (int r = 0; r < 4; ++r) l_run[mi][r] = l_run[mi][r] * alpha[r] + rs[r];
#pragma unroll
      for (int nf = 0; nf < 4; ++nf)
#pragma unroll
        for (int r = 0; r < 4; ++r) o[mi][nf][r] *= alpha[r];
#pragma unroll
      for (int nf = 0; nf < 8; ++nf)
#pragma unroll
        for (int r = 0; r < 4; ++r)
          Ps[(w * 32 + mi * 16 + lg * 4 + r) * 136 + nf * 16 + lr] = (bf16_t)s[mi][nf][r];
    }
    __syncthreads();

#pragma unroll
    for (int ks = 0; ks < 4; ++ks) {
      bf16x8 pa0 = *(const bf16x8*)&Ps[(w * 32 + lr) * 136 + ks * 32 + lg * 8];
      bf16x8 pa1 = *(const bf16x8*)&Ps[(w * 32 + 16 + lr) * 136 + ks * 32 + lg * 8];
#pragma unroll
      for (int nf = 0; nf < 4; ++nf) {
        bf16x8 vf = *(const bf16x8*)&Vs[(nf * 16 + lr) * 136 + ks * 32 + lg * 8];
        o[0][nf] = mfma16(pa0, vf, o[0][nf]);
        o[1][nf] = mfma16(pa1, vf, o[1][nf]);
      }
    }
  }

#pragma unroll
  for (int mi = 0; mi < 2; ++mi) {
    f32x4 inv;
#pragma unroll
    for (int r = 0; r < 4; ++r) inv[r] = 1.0f / l_run[mi][r];
#pragma unroll
    for (int nf = 0; nf < 4; ++nf)
#pragma unroll
      for (int r = 0; r < 4; ++r) {
        long row = rowQ + w * 32 + mi * 16 + lg * 4 + r;
        int col = h * 64 + nf * 16 + lr;
        Att[row * 1024 + col] = (bf16_t)(o[mi][nf][r] * inv[r]);
      }
  }
}

// ---------------- launch ----------------
extern "C" void kernel_launch(void* const* d_in, const int* in_sizes, int n_in,
                              void* d_out, int out_size, void* d_ws, size_t ws_size,
                              hipStream_t stream) {
  const float* x  = (const float*)d_in[0];
  const float* am = (const float*)d_in[1];
  const float* Wq = (const float*)d_in[2];
  const float* Wk = (const float*)d_in[3];
  const float* Wv = (const float*)d_in[4];
  const float* Wo = (const float*)d_in[5];
  float* out = (float*)d_out;

  char* ws = (char*)d_ws;
  bf16_t* qkv  = (bf16_t*)ws;                       // 16384*3072 bf16 = 100663296 B
  bf16_t* xb   = (bf16_t*)(ws + 100663296);         // 16384*1024 bf16 (reused as attended)
  bf16_t* wqkv = (bf16_t*)(ws + 134217728);         // 3072*1024 bf16 (rows: Wq,Wk,Wv)
  bf16_t* wob  = (bf16_t*)(ws + 140509184);         // 1024*1024 bf16

  const int kSmem = 147456;  // 3 ring slots x 48KB
  hipFuncSetAttribute(reinterpret_cast<const void*>(&gemm8p<bf16_t>),
                      hipFuncAttributeMaxDynamicSharedMemorySize, kSmem);
  hipFuncSetAttribute(reinterpret_cast<const void*>(&gemm8p<float>),
                      hipFuncAttributeMaxDynamicSharedMemorySize, kSmem);

  cvt_f32_bf16<<<8192, 256, 0, stream>>>(x, xb);
  cvt_f32_bf16<<<512, 256, 0, stream>>>(Wq, wqkv);
  cvt_f32_bf16<<<512, 256, 0, stream>>>(Wk, wqkv + 1048576);
  cvt_f32_bf16<<<512, 256, 0, stream>>>(Wv, wqkv + 2097152);
  cvt_f32_bf16<<<512, 256, 0, stream>>>(Wo, wob);

  // QKV projection: [16384,1024] x [3072,1024]^T -> [16384,3072] bf16
  gemm8p<bf16_t><<<dim3(64, 24), 512, kSmem, stream>>>(xb, wqkv, qkv, 16384, 3072, 1024);

  // local attention -> attended [16384,1024] bf16 (overwrites xb region)
  swa_kernel<<<2048, 256, 0, stream>>>(qkv, am, xb);

  // output projection: [16384,1024] x [1024,1024]^T -> d_out f32
  gemm8p<float><<<dim3(64, 8), 512, kSmem, stream>>>(xb, wob, out, 16384, 1024, 1024);
}

// Round 3
// 281.705 us; speedup vs baseline: 1.1412x; 1.0739x over previous
//
#include <hip/hip_runtime.h>
#include <stdint.h>

typedef __bf16 bf16_t;
typedef __bf16 bf16x8 __attribute__((ext_vector_type(8)));
typedef float f32x4 __attribute__((ext_vector_type(4)));

__device__ __forceinline__ f32x4 mfma16(bf16x8 a, bf16x8 b, f32x4 c) {
  return __builtin_amdgcn_mfma_f32_16x16x32_bf16(a, b, c, 0, 0, 0);
}

__device__ __forceinline__ void g2l16(const void* g, void* l) {
  __builtin_amdgcn_global_load_lds((const __attribute__((address_space(1))) void*)g,
                                   (__attribute__((address_space(3))) void*)l, 16, 0, 0);
}

#define FENCE() asm volatile("" ::: "memory")

// ---------------- f32 -> bf16 convert (vectorized, exact grid) ----------------
__global__ void __launch_bounds__(256) cvt_f32_bf16(const float* __restrict__ in,
                                                    bf16_t* __restrict__ out) {
  long i = ((long)blockIdx.x * 256 + threadIdx.x) * 8;
  float4 f0 = *(const float4*)(in + i);
  float4 f1 = *(const float4*)(in + i + 4);
  bf16x8 v;
  v[0] = (bf16_t)f0.x; v[1] = (bf16_t)f0.y; v[2] = (bf16_t)f0.z; v[3] = (bf16_t)f0.w;
  v[4] = (bf16_t)f1.x; v[5] = (bf16_t)f1.y; v[6] = (bf16_t)f1.z; v[7] = (bf16_t)f1.w;
  *(bf16x8*)(out + i) = v;
}

// ------- 256x256 4-phase GEMM: C[M,N] = A[M,K] * Bt[N,K]^T (m201 geometry) -------
// 512 threads = 8 waves (2M x 4N), per-wave C 128x64 (8x4 frags). BK=64.
// LDS: 2 x 64KB buffers (A 32KB + B 32KB), XOR-swizzled:
//   element(row, col16) at byte row*128 + ((col16 ^ (row&7))*16)
// Staging pre-swizzles the GLOBAL source so global_load_lds' linear dest lands swizzled.
// 4 phases/K-tile, 16 MFMA each; stage t+1 A in ph0, B in ph1; vmcnt(0) only at
// tile boundary (drains loads issued >=2 phases earlier -> ~free).
template <typename OutT>
__global__ void __launch_bounds__(512, 2) gemm256(const bf16_t* __restrict__ A,
                                                  const bf16_t* __restrict__ Bt,
                                                  OutT* __restrict__ C,
                                                  int M, int N, int K, int NBN) {
  extern __shared__ char smem[];
  const int t = threadIdx.x;
  const int w = t >> 6, l = t & 63;
  const int lr = l & 15, lg = l >> 4;
  const int wm = w >> 2, wn = w & 3;

  // bijective XCD chunking (nwg % 8 == 0), bn fastest within a chunk
  const int nwg = gridDim.x;
  const int flat = blockIdx.x;
  const int swz = (flat & 7) * (nwg >> 3) + (flat >> 3);
  const int bm = swz / NBN, bn = swz % NBN;
  const long rowA0 = (long)bm * 256;
  const long colC0 = (long)bn * 256;
  const int KT = K >> 6;

  // staging map: wave w covers rows [w*32, w*32+32) in 4 loads of 8 rows each;
  // lane l lands at row +=(l>>3), 16B-slot (l&7); logical col16 = (l&7)^(l>>3).
  const int colSwz = ((l & 7) ^ (l >> 3)) * 8;  // elements
  const bf16_t* gA = A + (rowA0 + w * 32 + (l >> 3)) * (long)K + colSwz;
  const bf16_t* gB = Bt + (colC0 + w * 32 + (l >> 3)) * (long)K + colSwz;
  const long K8 = (long)K * 8;

  // fragment-read swizzled 16B-slot offsets (frag rows have row&7 == lr&7)
  const int sx0 = (lg ^ (lr & 7)) * 16;
  const int sx1 = ((4 + lg) ^ (lr & 7)) * 16;
  const int aRow = (wm * 128 + lr) * 128;          // + i*2048
  const int bRow = 32768 + (wn * 64 + lr) * 128;   // + j*2048

  f32x4 acc[8][4] = {};

#define STAGE_A(buf, kt)                                          \
  {                                                               \
    char* _d = smem + (buf) * 65536 + w * 4096;                   \
    const long _ko = (long)(kt) * 64;                             \
    g2l16(gA + _ko, _d);                                          \
    g2l16(gA + K8 + _ko, _d + 1024);                              \
    g2l16(gA + 2 * K8 + _ko, _d + 2048);                          \
    g2l16(gA + 3 * K8 + _ko, _d + 3072);                          \
  }
#define STAGE_B(buf, kt)                                          \
  {                                                               \
    char* _d = smem + (buf) * 65536 + 32768 + w * 4096;           \
    const long _ko = (long)(kt) * 64;                             \
    g2l16(gB + _ko, _d);                                          \
    g2l16(gB + K8 + _ko, _d + 1024);                              \
    g2l16(gB + 2 * K8 + _ko, _d + 2048);                          \
    g2l16(gB + 3 * K8 + _ko, _d + 3072);                          \
  }

  // prologue: stage tile 0, drain, barrier
  STAGE_A(0, 0); STAGE_B(0, 0);
  FENCE();
  asm volatile("s_waitcnt vmcnt(0)" ::: "memory");
  __builtin_amdgcn_s_barrier();

  for (int kt = 0; kt < KT; ++kt) {
    const char* sb = smem + (kt & 1) * 65536;
    const int nb = (kt + 1) & 1;
    const bool ds = (kt + 1) < KT;

    bf16x8 bfr[4][2];

    // ---- phase 0: B all 8 frags + A m-frags 0,1 (12 ds_read_b128); stage A(t+1) ----
    {
      bf16x8 a0[2][2];
#pragma unroll
      for (int j = 0; j < 4; ++j) {
        bfr[j][0] = *(const bf16x8*)(sb + bRow + j * 2048 + sx0);
        bfr[j][1] = *(const bf16x8*)(sb + bRow + j * 2048 + sx1);
      }
#pragma unroll
      for (int i = 0; i < 2; ++i) {
        a0[i][0] = *(const bf16x8*)(sb + aRow + i * 2048 + sx0);
        a0[i][1] = *(const bf16x8*)(sb + aRow + i * 2048 + sx1);
      }
      if (ds) STAGE_A(nb, kt + 1);
      FENCE();
      __builtin_amdgcn_s_barrier();
      asm volatile("s_waitcnt lgkmcnt(0)" ::: "memory");
      __builtin_amdgcn_sched_barrier(0);
      __builtin_amdgcn_s_setprio(1);
#pragma unroll
      for (int i = 0; i < 2; ++i)
#pragma unroll
        for (int j = 0; j < 4; ++j) {
          acc[i][j] = mfma16(a0[i][0], bfr[j][0], acc[i][j]);
          acc[i][j] = mfma16(a0[i][1], bfr[j][1], acc[i][j]);
        }
      __builtin_amdgcn_s_setprio(0);
      __builtin_amdgcn_sched_barrier(0);
      FENCE();
      __builtin_amdgcn_s_barrier();
    }

    // ---- phases 1..3: A m-frags {2p,2p+1} (4 ds_read_b128); ph1 stages B(t+1) ----
#pragma unroll
    for (int p = 1; p < 4; ++p) {
      bf16x8 ap[2][2];
#pragma unroll
      for (int i = 0; i < 2; ++i) {
        ap[i][0] = *(const bf16x8*)(sb + aRow + (2 * p + i) * 2048 + sx0);
        ap[i][1] = *(const bf16x8*)(sb + aRow + (2 * p + i) * 2048 + sx1);
      }
      if (p == 1 && ds) STAGE_B(nb, kt + 1);
      FENCE();
      __builtin_amdgcn_s_barrier();
      asm volatile("s_waitcnt lgkmcnt(0)" ::: "memory");
      __builtin_amdgcn_sched_barrier(0);
      __builtin_amdgcn_s_setprio(1);
#pragma unroll
      for (int i = 0; i < 2; ++i)
#pragma unroll
        for (int j = 0; j < 4; ++j) {
          acc[2 * p + i][j] = mfma16(ap[i][0], bfr[j][0], acc[2 * p + i][j]);
          acc[2 * p + i][j] = mfma16(ap[i][1], bfr[j][1], acc[2 * p + i][j]);
        }
      __builtin_amdgcn_s_setprio(0);
      __builtin_amdgcn_sched_barrier(0);
      FENCE();
      if (p == 3 && ds) {
        // tile boundary: t+1's 8 loads (issued in ph0/ph1) must be in LDS
        asm volatile("s_waitcnt vmcnt(0)" ::: "memory");
      }
      __builtin_amdgcn_s_barrier();
    }
  }

  // epilogue
#pragma unroll
  for (int i = 0; i < 8; ++i)
#pragma unroll
    for (int j = 0; j < 4; ++j)
#pragma unroll
      for (int r = 0; r < 4; ++r) {
        long row = rowA0 + wm * 128 + i * 16 + lg * 4 + r;
        long col = colC0 + wn * 64 + j * 16 + lr;
        C[row * (long)N + col] = (OutT)acc[i][j][r];
      }
#undef STAGE_A
#undef STAGE_B
}

// ---------------- sliding-window attention (unchanged from round 2) ----------------
__global__ void __launch_bounds__(256) swa_kernel(const bf16_t* __restrict__ QKV,
                                                  const float* __restrict__ amask,
                                                  bf16_t* __restrict__ Att) {
  __shared__ bf16_t Vs[64 * 136];       // V^T, padded (row stride 272B)
  __shared__ bf16_t Ps[4 * 32 * 136];   // per-wave P, padded
  __shared__ float bias[128];

  const int idx = blockIdx.x;
  const int n = idx & 31;
  const int h = (idx >> 5) & 15;
  const int b = idx >> 9;
  const int t = threadIdx.x;
  const int w = t >> 6;
  const int l = t & 63;
  const int lr = l & 15;
  const int lg = l >> 4;

  const long rowQ = (long)b * 4096 + n * 128;

  bf16x8 qf[2][2];
#pragma unroll
  for (int mi = 0; mi < 2; ++mi)
#pragma unroll
    for (int ks = 0; ks < 2; ++ks)
      qf[mi][ks] = *(const bf16x8*)&QKV[(rowQ + w * 32 + mi * 16 + lr) * 3072 + h * 64 + ks * 32 + lg * 8];

  f32x4 o[2][4] = {};
  f32x4 m_run[2], l_run[2];
#pragma unroll
  for (int mi = 0; mi < 2; ++mi)
#pragma unroll
    for (int r = 0; r < 4; ++r) { m_run[mi][r] = -1e30f; l_run[mi][r] = 0.f; }

  const int kcLo = (n > 0) ? n - 1 : 0;
  const int kcHi = (n < 31) ? n + 1 : 31;
  for (int kc = kcLo; kc <= kcHi; ++kc) {
    const long kbase = (long)b * 4096 + (long)kc * 128;
    __syncthreads();
#pragma unroll
    for (int c = 0; c < 4; ++c) {
      int id = c * 256 + t;
      int kloc = id >> 3;
      int d0 = (id & 7) * 8;
      bf16x8 v = *(const bf16x8*)&QKV[(kbase + kloc) * 3072 + 2048 + h * 64 + d0];
#pragma unroll
      for (int j = 0; j < 8; ++j) Vs[(d0 + j) * 136 + kloc] = v[j];
    }
    if (t < 128) bias[t] = (amask[kbase + t] > 0.f) ? 0.f : -1e30f;
    __syncthreads();

    f32x4 s[2][8] = {};
    const bf16_t* Kb = QKV + kbase * 3072 + 1024 + h * 64;
#pragma unroll
    for (int nf = 0; nf < 8; ++nf) {
#pragma unroll
      for (int ks = 0; ks < 2; ++ks) {
        bf16x8 kf = *(const bf16x8*)&Kb[(nf * 16 + lr) * 3072 + ks * 32 + lg * 8];
        s[0][nf] = mfma16(qf[0][ks], kf, s[0][nf]);
        s[1][nf] = mfma16(qf[1][ks], kf, s[1][nf]);
      }
    }

#pragma unroll
    for (int mi = 0; mi < 2; ++mi) {
      f32x4 rm;
#pragma unroll
      for (int r = 0; r < 4; ++r) rm[r] = -3e30f;
#pragma unroll
      for (int nf = 0; nf < 8; ++nf) {
        float bv = bias[nf * 16 + lr];
#pragma unroll
        for (int r = 0; r < 4; ++r) {
          float sv = s[mi][nf][r] * 0.125f + bv;
          s[mi][nf][r] = sv;
          rm[r] = fmaxf(rm[r], sv);
        }
      }
#pragma unroll
      for (int off = 8; off > 0; off >>= 1)
#pragma unroll
        for (int r = 0; r < 4; ++r) rm[r] = fmaxf(rm[r], __shfl_xor(rm[r], off));
      f32x4 mnew, alpha, rs;
#pragma unroll
      for (int r = 0; r < 4; ++r) {
        mnew[r] = fmaxf(m_run[mi][r], rm[r]);
        alpha[r] = __expf(m_run[mi][r] - mnew[r]);
        m_run[mi][r] = mnew[r];
        rs[r] = 0.f;
      }
#pragma unroll
      for (int nf = 0; nf < 8; ++nf)
#pragma unroll
        for (int r = 0; r < 4; ++r) {
          float p = __expf(s[mi][nf][r] - mnew[r]);
          s[mi][nf][r] = p;
          rs[r] += p;
        }
#pragma unroll
      for (int off = 8; off > 0; off >>= 1)
#pragma unroll
        for (int r = 0; r < 4; ++r) rs[r] += __shfl_xor(rs[r], off);
#pragma unroll
      for (int r = 0; r < 4; ++r) l_run[mi][r] = l_run[mi][r] * alpha[r] + rs[r];
#pragma unroll
      for (int nf = 0; nf < 4; ++nf)
#pragma unroll
        for (int r = 0; r < 4; ++r) o[mi][nf][r] *= alpha[r];
#pragma unroll
      for (int nf = 0; nf < 8; ++nf)
#pragma unroll
        for (int r = 0; r < 4; ++r)
          Ps[(w * 32 + mi * 16 + lg * 4 + r) * 136 + nf * 16 + lr] = (bf16_t)s[mi][nf][r];
    }
    __syncthreads();

#pragma unroll
    for (int ks = 0; ks < 4; ++ks) {
      bf16x8 pa0 = *(const bf16x8*)&Ps[(w * 32 + lr) * 136 + ks * 32 + lg * 8];
      bf16x8 pa1 = *(const bf16x8*)&Ps[(w * 32 + 16 + lr) * 136 + ks * 32 + lg * 8];
#pragma unroll
      for (int nf = 0; nf < 4; ++nf) {
        bf16x8 vf = *(const bf16x8*)&Vs[(nf * 16 + lr) * 136 + ks * 32 + lg * 8];
        o[0][nf] = mfma16(pa0, vf, o[0][nf]);
        o[1][nf] = mfma16(pa1, vf, o[1][nf]);
      }
    }
  }

#pragma unroll
  for (int mi = 0; mi < 2; ++mi) {
    f32x4 inv;
#pragma unroll
    for (int r = 0; r < 4; ++r) inv[r] = 1.0f / l_run[mi][r];
#pragma unroll
    for (int nf = 0; nf < 4; ++nf)
#pragma unroll
      for (int r = 0; r < 4; ++r) {
        long row = rowQ + w * 32 + mi * 16 + lg * 4 + r;
        int col = h * 64 + nf * 16 + lr;
        Att[row * 1024 + col] = (bf16_t)(o[mi][nf][r] * inv[r]);
      }
  }
}

// ---------------- launch ----------------
extern "C" void kernel_launch(void* const* d_in, const int* in_sizes, int n_in,
                              void* d_out, int out_size, void* d_ws, size_t ws_size,
                              hipStream_t stream) {
  const float* x  = (const float*)d_in[0];
  const float* am = (const float*)d_in[1];
  const float* Wq = (const float*)d_in[2];
  const float* Wk = (const float*)d_in[3];
  const float* Wv = (const float*)d_in[4];
  const float* Wo = (const float*)d_in[5];
  float* out = (float*)d_out;

  char* ws = (char*)d_ws;
  bf16_t* qkv  = (bf16_t*)ws;                       // 16384*3072 bf16 = 100663296 B
  bf16_t* xb   = (bf16_t*)(ws + 100663296);         // 16384*1024 bf16 (reused as attended)
  bf16_t* wqkv = (bf16_t*)(ws + 134217728);         // 3072*1024 bf16 (rows: Wq,Wk,Wv)
  bf16_t* wob  = (bf16_t*)(ws + 140509184);         // 1024*1024 bf16

  const int kSmem = 131072;  // 2 x 64KB double buffer
  hipFuncSetAttribute(reinterpret_cast<const void*>(&gemm256<bf16_t>),
                      hipFuncAttributeMaxDynamicSharedMemorySize, kSmem);
  hipFuncSetAttribute(reinterpret_cast<const void*>(&gemm256<float>),
                      hipFuncAttributeMaxDynamicSharedMemorySize, kSmem);

  cvt_f32_bf16<<<8192, 256, 0, stream>>>(x, xb);
  cvt_f32_bf16<<<512, 256, 0, stream>>>(Wq, wqkv);
  cvt_f32_bf16<<<512, 256, 0, stream>>>(Wk, wqkv + 1048576);
  cvt_f32_bf16<<<512, 256, 0, stream>>>(Wv, wqkv + 2097152);
  cvt_f32_bf16<<<512, 256, 0, stream>>>(Wo, wob);

  // QKV projection: [16384,1024] x [3072,1024]^T -> [16384,3072] bf16
  // grid: 64 bm x 12 bn = 768 blocks (multiple of 8 for XCD chunking)
  gemm256<bf16_t><<<768, 512, kSmem, stream>>>(xb, wqkv, qkv, 16384, 3072, 1024, 12);

  // local attention -> attended [16384,1024] bf16 (overwrites xb region)
  swa_kernel<<<2048, 256, 0, stream>>>(qkv, am, xb);

  // output projection: [16384,1024] x [1024,1024]^T -> d_out f32 (64 x 4 = 256 blocks)
  gemm256<float><<<256, 512, kSmem, stream>>>(xb, wob, out, 16384, 1024, 1024, 4);
}

// Round 5
// 229.883 us; speedup vs baseline: 1.3985x; 1.2254x over previous
//
#include <hip/hip_runtime.h>
#include <stdint.h>

typedef __bf16 bf16_t;
typedef __bf16 bf16x8 __attribute__((ext_vector_type(8)));
typedef __bf16 bf16x4 __attribute__((ext_vector_type(4)));
typedef float f32x4 __attribute__((ext_vector_type(4)));

__device__ __forceinline__ f32x4 mfma16(bf16x8 a, bf16x8 b, f32x4 c) {
  return __builtin_amdgcn_mfma_f32_16x16x32_bf16(a, b, c, 0, 0, 0);
}

__device__ __forceinline__ void g2l16(const void* g, void* l) {
  __builtin_amdgcn_global_load_lds((const __attribute__((address_space(1))) void*)g,
                                   (__attribute__((address_space(3))) void*)l, 16, 0, 0);
}

#define FENCE() asm volatile("" ::: "memory")

// ---------------- f32 -> bf16 convert ----------------
__global__ void __launch_bounds__(256) cvt_f32_bf16(const float* __restrict__ in,
                                                    bf16_t* __restrict__ out) {
  long i = ((long)blockIdx.x * 256 + threadIdx.x) * 8;
  float4 f0 = *(const float4*)(in + i);
  float4 f1 = *(const float4*)(in + i + 4);
  bf16x8 v;
  v[0] = (bf16_t)f0.x; v[1] = (bf16_t)f0.y; v[2] = (bf16_t)f0.z; v[3] = (bf16_t)f0.w;
  v[4] = (bf16_t)f1.x; v[5] = (bf16_t)f1.y; v[6] = (bf16_t)f1.z; v[7] = (bf16_t)f1.w;
  *(bf16x8*)(out + i) = v;
}

// ------- 256x256 4-phase GEMM: C[M,N] = A[M,K] * Bt[N,K]^T (verified round 3) -------
template <typename OutT>
__global__ void __launch_bounds__(512, 2) gemm256(const bf16_t* __restrict__ A,
                                                  const bf16_t* __restrict__ Bt,
                                                  OutT* __restrict__ C,
                                                  int M, int N, int K, int NBN) {
  extern __shared__ char smem[];
  const int t = threadIdx.x;
  const int w = t >> 6, l = t & 63;
  const int lr = l & 15, lg = l >> 4;
  const int wm = w >> 2, wn = w & 3;

  const int nwg = gridDim.x;
  const int flat = blockIdx.x;
  const int swz = (flat & 7) * (nwg >> 3) + (flat >> 3);
  const int bm = swz / NBN, bn = swz % NBN;
  const long rowA0 = (long)bm * 256;
  const long colC0 = (long)bn * 256;
  const int KT = K >> 6;

  const int colSwz = ((l & 7) ^ (l >> 3)) * 8;
  const bf16_t* gA = A + (rowA0 + w * 32 + (l >> 3)) * (long)K + colSwz;
  const bf16_t* gB = Bt + (colC0 + w * 32 + (l >> 3)) * (long)K + colSwz;
  const long K8 = (long)K * 8;

  const int sx0 = (lg ^ (lr & 7)) * 16;
  const int sx1 = ((4 + lg) ^ (lr & 7)) * 16;
  const int aRow = (wm * 128 + lr) * 128;
  const int bRow = 32768 + (wn * 64 + lr) * 128;

  f32x4 acc[8][4] = {};

#define STAGE_A(buf, kt)                                          \
  {                                                               \
    char* _d = smem + (buf) * 65536 + w * 4096;                   \
    const long _ko = (long)(kt) * 64;                             \
    g2l16(gA + _ko, _d);                                          \
    g2l16(gA + K8 + _ko, _d + 1024);                              \
    g2l16(gA + 2 * K8 + _ko, _d + 2048);                          \
    g2l16(gA + 3 * K8 + _ko, _d + 3072);                          \
  }
#define STAGE_B(buf, kt)                                          \
  {                                                               \
    char* _d = smem + (buf) * 65536 + 32768 + w * 4096;           \
    const long _ko = (long)(kt) * 64;                             \
    g2l16(gB + _ko, _d);                                          \
    g2l16(gB + K8 + _ko, _d + 1024);                              \
    g2l16(gB + 2 * K8 + _ko, _d + 2048);                          \
    g2l16(gB + 3 * K8 + _ko, _d + 3072);                          \
  }

  STAGE_A(0, 0); STAGE_B(0, 0);
  FENCE();
  asm volatile("s_waitcnt vmcnt(0)" ::: "memory");
  __builtin_amdgcn_s_barrier();

  for (int kt = 0; kt < KT; ++kt) {
    const char* sb = smem + (kt & 1) * 65536;
    const int nb = (kt + 1) & 1;
    const bool ds = (kt + 1) < KT;

    bf16x8 bfr[4][2];

    {
      bf16x8 a0[2][2];
#pragma unroll
      for (int j = 0; j < 4; ++j) {
        bfr[j][0] = *(const bf16x8*)(sb + bRow + j * 2048 + sx0);
        bfr[j][1] = *(const bf16x8*)(sb + bRow + j * 2048 + sx1);
      }
#pragma unroll
      for (int i = 0; i < 2; ++i) {
        a0[i][0] = *(const bf16x8*)(sb + aRow + i * 2048 + sx0);
        a0[i][1] = *(const bf16x8*)(sb + aRow + i * 2048 + sx1);
      }
      if (ds) STAGE_A(nb, kt + 1);
      FENCE();
      __builtin_amdgcn_s_barrier();
      asm volatile("s_waitcnt lgkmcnt(0)" ::: "memory");
      __builtin_amdgcn_sched_barrier(0);
      __builtin_amdgcn_s_setprio(1);
#pragma unroll
      for (int i = 0; i < 2; ++i)
#pragma unroll
        for (int j = 0; j < 4; ++j) {
          acc[i][j] = mfma16(a0[i][0], bfr[j][0], acc[i][j]);
          acc[i][j] = mfma16(a0[i][1], bfr[j][1], acc[i][j]);
        }
      __builtin_amdgcn_s_setprio(0);
      __builtin_amdgcn_sched_barrier(0);
      FENCE();
      __builtin_amdgcn_s_barrier();
    }

#pragma unroll
    for (int p = 1; p < 4; ++p) {
      bf16x8 ap[2][2];
#pragma unroll
      for (int i = 0; i < 2; ++i) {
        ap[i][0] = *(const bf16x8*)(sb + aRow + (2 * p + i) * 2048 + sx0);
        ap[i][1] = *(const bf16x8*)(sb + aRow + (2 * p + i) * 2048 + sx1);
      }
      if (p == 1 && ds) STAGE_B(nb, kt + 1);
      FENCE();
      __builtin_amdgcn_s_barrier();
      asm volatile("s_waitcnt lgkmcnt(0)" ::: "memory");
      __builtin_amdgcn_sched_barrier(0);
      __builtin_amdgcn_s_setprio(1);
#pragma unroll
      for (int i = 0; i < 2; ++i)
#pragma unroll
        for (int j = 0; j < 4; ++j) {
          acc[2 * p + i][j] = mfma16(ap[i][0], bfr[j][0], acc[2 * p + i][j]);
          acc[2 * p + i][j] = mfma16(ap[i][1], bfr[j][1], acc[2 * p + i][j]);
        }
      __builtin_amdgcn_s_setprio(0);
      __builtin_amdgcn_sched_barrier(0);
      FENCE();
      if (p == 3 && ds) {
        asm volatile("s_waitcnt vmcnt(0)" ::: "memory");
      }
      __builtin_amdgcn_s_barrier();
    }
  }

#pragma unroll
  for (int i = 0; i < 8; ++i)
#pragma unroll
    for (int j = 0; j < 4; ++j)
#pragma unroll
      for (int r = 0; r < 4; ++r) {
        long row = rowA0 + wm * 128 + i * 16 + lg * 4 + r;
        long col = colC0 + wn * 64 + j * 16 + lr;
        C[row * (long)N + col] = (OutT)acc[i][j][r];
      }
#undef STAGE_A
#undef STAGE_B
}

// ---------------- sliding-window attention, swapped-QK^T, pre-transposed V ----------------
// QK: [16384, 2048] bf16 (Q cols 0..1023, K cols 1024..2047, feature = h*64+d)
// VT: [1024, 16384] bf16 (row = h*64+d, col = b*4096+token)  -- produced by the Vt GEMM
// 1 block = (b,h,window); 8 waves x 16 q-rows. S^T = mfma(K,Q): lane lr owns q-row lr.
// LDS: Ks 16KB [128 krow][8 slot16], phys slot = logical ^ (krow&7) (g2l pre-swizzled src)
//      Vs 16KB [64 d][16 slot16],    phys slot = logical ^ (d&15)   (g2l pre-swizzled src)
//      bias 512B; Psw per-wave 4352B: [16 q][272B keys] (b64 writes, b128 reads)
__global__ void __launch_bounds__(512, 4) swa3(const bf16_t* __restrict__ QK,
                                               const bf16_t* __restrict__ VT,
                                               const float* __restrict__ amask,
                                               bf16_t* __restrict__ Att) {
  extern __shared__ char lds[];
  bf16_t* Ks = (bf16_t*)lds;
  bf16_t* Vs = (bf16_t*)(lds + 16384);
  float* bias = (float*)(lds + 32768);
  const int t = threadIdx.x, w = t >> 6, l = t & 63, lr = l & 15, lg = l >> 4;
  char* Psw = lds + 33280 + w * 4352;

  // XCD chunking: adjacent-n blocks (sharing K/V chunks) on the same XCD
  const int idx = (blockIdx.x & 7) * 256 + (blockIdx.x >> 3);
  const int n = idx & 31, h = (idx >> 5) & 15, b = idx >> 9;
  const long rowQ = (long)b * 4096 + n * 128;

  // Q as B-operand frags (col = q = lr, k elems = d at lg*8)
  bf16x8 qf[2];
#pragma unroll
  for (int ks = 0; ks < 2; ++ks)
    qf[ks] = *(const bf16x8*)&QK[(rowQ + w * 16 + lr) * 2048 + h * 64 + ks * 32 + lg * 8];

  f32x4 oT[4] = {};                 // O^T frags (lane: q=lr, d = df*16 + lg*4 + r)
  float m_run = -1e30f, l_run = 0.f;

  const int kcLo = (n > 0) ? n - 1 : 0;
  const int kcHi = (n < 31) ? n + 1 : 31;
  const long kbase0 = (long)b * 4096 + (long)kcLo * 128;

  // K staging: thread t -> row t>>3, phys slot t&7; src col16 = (t&7)^(row&7)
  const int kcol = ((t & 7) ^ ((t >> 3) & 7)) * 8;
  const bf16_t* gK0 = QK + (kbase0 + (t >> 3)) * 2048 + 1024 + h * 64 + kcol;
  const bf16_t* gK1 = gK0 + (long)64 * 2048;
  // V staging: part q in {0,1}: flat = q*512+t -> d-row flat>>4, phys slot flat&15;
  // src col16 = (flat&15)^(row&15). (512+t)>>4 & 15 == (t>>4)&15, so same col for part 1.
  const int vrow = t >> 4;
  const int vcol = ((t & 15) ^ ((t >> 4) & 15)) * 8;
  const bf16_t* gV0 = VT + ((long)h * 64 + vrow) * 16384 + (long)b * 4096 + (long)kcLo * 128 + vcol;
  const bf16_t* gV1 = gV0 + (long)32 * 16384;
  const float* gM = amask + kbase0 + (t & 31) * 4;

  bf16_t* lK0 = Ks + t * 8;
  bf16_t* lK1 = Ks + 4096 + t * 8;
  bf16_t* lV0 = Vs + t * 8;
  bf16_t* lV1 = Vs + 4096 + t * 8;

  const int nch = kcHi - kcLo + 1;
  for (int c = 0; c < nch; ++c) {
    __syncthreads();  // previous chunk's Ks/Vs reads complete
    g2l16(gK0, lK0); g2l16(gK1, lK1);
    g2l16(gV0, lV0); g2l16(gV1, lV1);
    if (t < 32) {
      float4 mv = *(const float4*)gM;
      float4 bv;
      bv.x = mv.x > 0.f ? 0.f : -1e30f;
      bv.y = mv.y > 0.f ? 0.f : -1e30f;
      bv.z = mv.z > 0.f ? 0.f : -1e30f;
      bv.w = mv.w > 0.f ? 0.f : -1e30f;
      *(float4*)&bias[t * 4] = bv;
    }
    FENCE();
    asm volatile("s_waitcnt vmcnt(0)" ::: "memory");
    __syncthreads();

    // ---- QK^T -> S^T (lane: q=lr, keys = kb*16 + lg*4 + r) ----
    f32x4 s[8];
#pragma unroll
    for (int kb = 0; kb < 8; ++kb) {
      f32x4 z = {};
#pragma unroll
      for (int ks = 0; ks < 2; ++ks) {
        bf16x8 kA = *(const bf16x8*)&Ks[(kb * 16 + lr) * 64 + (((ks * 4 + lg) ^ (lr & 7)) * 8)];
        z = mfma16(kA, qf[ks], z);
      }
      s[kb] = z;
    }

    // ---- online softmax: per-lane (q = lr) + reduce across lg groups ----
    float mt = -3e30f;
#pragma unroll
    for (int kb = 0; kb < 8; ++kb) {
      f32x4 bb = *(const f32x4*)&bias[kb * 16 + lg * 4];
#pragma unroll
      for (int r = 0; r < 4; ++r) {
        float sv = s[kb][r] * 0.125f + bb[r];
        s[kb][r] = sv;
        mt = fmaxf(mt, sv);
      }
    }
    mt = fmaxf(mt, __shfl_xor(mt, 16));
    mt = fmaxf(mt, __shfl_xor(mt, 32));
    float mnew = fmaxf(m_run, mt);
    float alpha = __expf(m_run - mnew);
    m_run = mnew;
    float rs = 0.f;
#pragma unroll
    for (int kb = 0; kb < 8; ++kb)
#pragma unroll
      for (int r = 0; r < 4; ++r) {
        float p = __expf(s[kb][r] - mnew);
        s[kb][r] = p;
        rs += p;
      }
    rs += __shfl_xor(rs, 16);
    rs += __shfl_xor(rs, 32);
    l_run = l_run * alpha + rs;
#pragma unroll
    for (int df = 0; df < 4; ++df)
#pragma unroll
      for (int r = 0; r < 4; ++r) oT[df][r] *= alpha;

    // ---- P^T -> per-wave LDS (b64 packed), then fence before cross-lane reads ----
#pragma unroll
    for (int kb = 0; kb < 8; ++kb) {
      bf16x4 pv;
      pv[0] = (bf16_t)s[kb][0]; pv[1] = (bf16_t)s[kb][1];
      pv[2] = (bf16_t)s[kb][2]; pv[3] = (bf16_t)s[kb][3];
      *(bf16x4*)(Psw + lr * 272 + kb * 32 + lg * 8) = pv;
    }
    asm volatile("s_waitcnt lgkmcnt(0)" ::: "memory");
    __builtin_amdgcn_sched_barrier(0);

    // ---- PV: O^T[d,q] += V^T x P^T (plain b128 reads, swizzled Vs) ----
#pragma unroll
    for (int ks = 0; ks < 4; ++ks) {
      bf16x8 pB = *(const bf16x8*)(Psw + lr * 272 + ks * 64 + lg * 16);
#pragma unroll
      for (int df = 0; df < 4; ++df) {
        bf16x8 vA = *(const bf16x8*)&Vs[(df * 16 + lr) * 128 + (((ks * 4 + lg) ^ lr) * 8)];
        oT[df] = mfma16(vA, pB, oT[df]);
      }
    }

    gK0 += (long)128 * 2048; gK1 += (long)128 * 2048;
    gV0 += 128; gV1 += 128;
    gM += 128;
  }

  // ---- epilogue: normalize, transpose O^T via per-wave Psw, coalesced store ----
  float inv = 1.f / l_run;
#pragma unroll
  for (int df = 0; df < 4; ++df) {
    bf16x4 ov;
#pragma unroll
    for (int r = 0; r < 4; ++r) ov[r] = (bf16_t)(oT[df][r] * inv);
    *(bf16x4*)(Psw + lr * 272 + df * 32 + lg * 8) = ov;  // Os[q=lr][d]
  }
  asm volatile("s_waitcnt lgkmcnt(0)" ::: "memory");
  __builtin_amdgcn_sched_barrier(0);
  const char* myP = lds + 33280 + w * 4352;
  bf16x8 r0 = *(const bf16x8*)(myP + (l >> 2) * 272 + (l & 3) * 32);
  bf16x8 r1 = *(const bf16x8*)(myP + (l >> 2) * 272 + (l & 3) * 32 + 16);
  long orow = rowQ + w * 16 + (l >> 2);
  bf16_t* op = Att + orow * 1024 + h * 64 + (l & 3) * 16;
  *(bf16x8*)op = r0;
  *(bf16x8*)(op + 8) = r1;
}

// ---------------- launch ----------------
extern "C" void kernel_launch(void* const* d_in, const int* in_sizes, int n_in,
                              void* d_out, int out_size, void* d_ws, size_t ws_size,
                              hipStream_t stream) {
  const float* x  = (const float*)d_in[0];
  const float* am = (const float*)d_in[1];
  const float* Wq = (const float*)d_in[2];
  const float* Wk = (const float*)d_in[3];
  const float* Wv = (const float*)d_in[4];
  const float* Wo = (const float*)d_in[5];
  float* out = (float*)d_out;

  char* ws = (char*)d_ws;
  bf16_t* qk  = (bf16_t*)ws;                        // [16384,2048] = 67108864 B
  bf16_t* vt  = (bf16_t*)(ws + 67108864);           // [1024,16384] = 33554432 B
  bf16_t* xbx = (bf16_t*)(ws + 100663296);          // [16384,1024] bf16 x; reused as attended
  bf16_t* wqk = (bf16_t*)(ws + 134217728);          // [2048,1024] rows: Wq, Wk
  bf16_t* wvb = (bf16_t*)(ws + 138412032);          // [1024,1024] Wv
  bf16_t* wob = (bf16_t*)(ws + 140509184);          // [1024,1024] Wo

  const int kSmemG = 131072;
  hipFuncSetAttribute(reinterpret_cast<const void*>(&gemm256<bf16_t>),
                      hipFuncAttributeMaxDynamicSharedMemorySize, kSmemG);
  hipFuncSetAttribute(reinterpret_cast<const void*>(&gemm256<float>),
                      hipFuncAttributeMaxDynamicSharedMemorySize, kSmemG);
  const int kSmemS = 68096;  // Ks 16K + Vs 16K + bias 512 + Psw 8*4352
  hipFuncSetAttribute(reinterpret_cast<const void*>(&swa3),
                      hipFuncAttributeMaxDynamicSharedMemorySize, kSmemS);

  cvt_f32_bf16<<<8192, 256, 0, stream>>>(x, xbx);
  cvt_f32_bf16<<<512, 256, 0, stream>>>(Wq, wqk);
  cvt_f32_bf16<<<512, 256, 0, stream>>>(Wk, wqk + 1048576);
  cvt_f32_bf16<<<512, 256, 0, stream>>>(Wv, wvb);
  cvt_f32_bf16<<<512, 256, 0, stream>>>(Wo, wob);

  // QK projection: [16384,1024] x [2048,1024]^T -> qk [16384,2048]
  gemm256<bf16_t><<<512, 512, kSmemG, stream>>>(xbx, wqk, qk, 16384, 2048, 1024, 8);

  // V^T projection: Vt = Wv * x^T : A=[1024,1024], Bt=[16384,1024] -> vt [1024,16384]
  gemm256<bf16_t><<<256, 512, kSmemG, stream>>>(wvb, xbx, vt, 1024, 16384, 1024, 64);

  // local attention -> attended [16384,1024] bf16 (overwrites xbx)
  swa3<<<2048, 512, kSmemS, stream>>>(qk, vt, am, xbx);

  // output projection: [16384,1024] x [1024,1024]^T -> d_out f32
  gemm256<float><<<256, 512, kSmemG, stream>>>(xbx, wob, out, 16384, 1024, 1024, 4);
}

// Round 6
// 229.667 us; speedup vs baseline: 1.3998x; 1.0009x over previous
//
#include <hip/hip_runtime.h>
#include <stdint.h>

typedef __bf16 bf16_t;
typedef __bf16 bf16x8 __attribute__((ext_vector_type(8)));
typedef __bf16 bf16x4 __attribute__((ext_vector_type(4)));
typedef float f32x4 __attribute__((ext_vector_type(4)));

__device__ __forceinline__ f32x4 mfma16(bf16x8 a, bf16x8 b, f32x4 c) {
  return __builtin_amdgcn_mfma_f32_16x16x32_bf16(a, b, c, 0, 0, 0);
}

__device__ __forceinline__ void g2l16(const void* g, void* l) {
  __builtin_amdgcn_global_load_lds((const __attribute__((address_space(1))) void*)g,
                                   (__attribute__((address_space(3))) void*)l, 16, 0, 0);
}

#define FENCE() asm volatile("" ::: "memory")

// ---------------- f32 -> bf16 convert ----------------
__global__ void __launch_bounds__(256) cvt_f32_bf16(const float* __restrict__ in,
                                                    bf16_t* __restrict__ out) {
  long i = ((long)blockIdx.x * 256 + threadIdx.x) * 8;
  float4 f0 = *(const float4*)(in + i);
  float4 f1 = *(const float4*)(in + i + 4);
  bf16x8 v;
  v[0] = (bf16_t)f0.x; v[1] = (bf16_t)f0.y; v[2] = (bf16_t)f0.z; v[3] = (bf16_t)f0.w;
  v[4] = (bf16_t)f1.x; v[5] = (bf16_t)f1.y; v[6] = (bf16_t)f1.z; v[7] = (bf16_t)f1.w;
  *(bf16x8*)(out + i) = v;
}

// ------- 256x256 2-phase GEMM: C[M,N] = A[M,K] * Bt[N,K]^T -------
// 512 threads = 8 waves (2M x 4N), per-wave C 128x64. BK=64. 2x64KB LDS dbuf,
// XOR-swizzled (phys slot16 = logical ^ (row&7)); g2l with pre-swizzled source.
// 2 phases/K-tile, 32 MFMA each (phase overhead ~constant -> amortize with big phases).
template <typename OutT>
__global__ void __launch_bounds__(512, 2) gemm256(const bf16_t* __restrict__ A,
                                                  const bf16_t* __restrict__ Bt,
                                                  OutT* __restrict__ C,
                                                  int M, int N, int K, int NBN) {
  extern __shared__ char smem[];
  const int t = threadIdx.x;
  const int w = t >> 6, l = t & 63;
  const int lr = l & 15, lg = l >> 4;
  const int wm = w >> 2, wn = w & 3;

  const int nwg = gridDim.x;
  const int flat = blockIdx.x;
  const int swz = (flat & 7) * (nwg >> 3) + (flat >> 3);
  const int bm = swz / NBN, bn = swz % NBN;
  const long rowA0 = (long)bm * 256;
  const long colC0 = (long)bn * 256;
  const int KT = K >> 6;

  const int colSwz = ((l & 7) ^ (l >> 3)) * 8;
  const bf16_t* gA = A + (rowA0 + w * 32 + (l >> 3)) * (long)K + colSwz;
  const bf16_t* gB = Bt + (colC0 + w * 32 + (l >> 3)) * (long)K + colSwz;
  const long K8 = (long)K * 8;

  const int sx0 = (lg ^ (lr & 7)) * 16;
  const int sx1 = ((4 + lg) ^ (lr & 7)) * 16;
  const int aRow = (wm * 128 + lr) * 128;
  const int bRow = 32768 + (wn * 64 + lr) * 128;

  f32x4 acc[8][4] = {};

#define STAGE_A(buf, kt)                                          \
  {                                                               \
    char* _d = smem + (buf) * 65536 + w * 4096;                   \
    const long _ko = (long)(kt) * 64;                             \
    g2l16(gA + _ko, _d);                                          \
    g2l16(gA + K8 + _ko, _d + 1024);                              \
    g2l16(gA + 2 * K8 + _ko, _d + 2048);                          \
    g2l16(gA + 3 * K8 + _ko, _d + 3072);                          \
  }
#define STAGE_B(buf, kt)                                          \
  {                                                               \
    char* _d = smem + (buf) * 65536 + 32768 + w * 4096;           \
    const long _ko = (long)(kt) * 64;                             \
    g2l16(gB + _ko, _d);                                          \
    g2l16(gB + K8 + _ko, _d + 1024);                              \
    g2l16(gB + 2 * K8 + _ko, _d + 2048);                          \
    g2l16(gB + 3 * K8 + _ko, _d + 3072);                          \
  }

  STAGE_A(0, 0); STAGE_B(0, 0);
  FENCE();
  asm volatile("s_waitcnt vmcnt(0)" ::: "memory");
  __builtin_amdgcn_s_barrier();

  for (int kt = 0; kt < KT; ++kt) {
    const char* sb = smem + (kt & 1) * 65536;
    const int nb = (kt + 1) & 1;
    const bool ds = (kt + 1) < KT;

    bf16x8 bfr[4][2];

    // ---- phase 0: B all 8 frags + A m-frags 0..3 (16 ds_read_b128); stage A(t+1);
    //      32 MFMA (acc[0..3]) ----
    {
      bf16x8 a0[4][2];
#pragma unroll
      for (int j = 0; j < 4; ++j) {
        bfr[j][0] = *(const bf16x8*)(sb + bRow + j * 2048 + sx0);
        bfr[j][1] = *(const bf16x8*)(sb + bRow + j * 2048 + sx1);
      }
#pragma unroll
      for (int i = 0; i < 4; ++i) {
        a0[i][0] = *(const bf16x8*)(sb + aRow + i * 2048 + sx0);
        a0[i][1] = *(const bf16x8*)(sb + aRow + i * 2048 + sx1);
      }
      if (ds) STAGE_A(nb, kt + 1);
      FENCE();
      __builtin_amdgcn_s_barrier();
      asm volatile("s_waitcnt lgkmcnt(0)" ::: "memory");
      __builtin_amdgcn_sched_barrier(0);
      __builtin_amdgcn_s_setprio(1);
#pragma unroll
      for (int i = 0; i < 4; ++i)
#pragma unroll
        for (int j = 0; j < 4; ++j) {
          acc[i][j] = mfma16(a0[i][0], bfr[j][0], acc[i][j]);
          acc[i][j] = mfma16(a0[i][1], bfr[j][1], acc[i][j]);
        }
      __builtin_amdgcn_s_setprio(0);
      __builtin_amdgcn_sched_barrier(0);
      FENCE();
      __builtin_amdgcn_s_barrier();
    }

    // ---- phase 1: A m-frags 4..7 (8 ds_read_b128); stage B(t+1); 32 MFMA ----
    {
      bf16x8 a1[4][2];
#pragma unroll
      for (int i = 0; i < 4; ++i) {
        a1[i][0] = *(const bf16x8*)(sb + aRow + (4 + i) * 2048 + sx0);
        a1[i][1] = *(const bf16x8*)(sb + aRow + (4 + i) * 2048 + sx1);
      }
      if (ds) STAGE_B(nb, kt + 1);
      FENCE();
      __builtin_amdgcn_s_barrier();
      asm volatile("s_waitcnt lgkmcnt(0)" ::: "memory");
      __builtin_amdgcn_sched_barrier(0);
      __builtin_amdgcn_s_setprio(1);
#pragma unroll
      for (int i = 0; i < 4; ++i)
#pragma unroll
        for (int j = 0; j < 4; ++j) {
          acc[4 + i][j] = mfma16(a1[i][0], bfr[j][0], acc[4 + i][j]);
          acc[4 + i][j] = mfma16(a1[i][1], bfr[j][1], acc[4 + i][j]);
        }
      __builtin_amdgcn_s_setprio(0);
      __builtin_amdgcn_sched_barrier(0);
      FENCE();
      if (ds) {
        // tile boundary: t+1's 8 loads (issued this tile) must be in LDS
        asm volatile("s_waitcnt vmcnt(0)" ::: "memory");
      }
      __builtin_amdgcn_s_barrier();
    }
  }

  // epilogue
#pragma unroll
  for (int i = 0; i < 8; ++i)
#pragma unroll
    for (int j = 0; j < 4; ++j)
#pragma unroll
      for (int r = 0; r < 4; ++r) {
        long row = rowA0 + wm * 128 + i * 16 + lg * 4 + r;
        long col = colC0 + wn * 64 + j * 16 + lr;
        C[row * (long)N + col] = (OutT)acc[i][j][r];
      }
#undef STAGE_A
#undef STAGE_B
}

// ---------------- sliding-window attention, pipelined K/V staging ----------------
// QK: [16384, 2048] bf16 (Q cols 0..1023, K cols 1024..2047); VT: [1024, 16384] bf16.
// 1 block = (b,h,window); 8 waves x 16 q-rows; swapped QK^T (lane lr owns q-row).
// Single K/V LDS buffers, software-pipelined with counted vmcnt:
//   stage K(c+1) after post-QK barrier (Ks dead), V(c+1) after post-PV barrier.
//   Waits: vmcnt(2) (in-order: oldest 2 = the needed stage). Mask bias preloaded
//   in prologue so no per-lane vmem pollutes the wave's vmcnt ledger.
__global__ void __launch_bounds__(512, 4) swa3(const bf16_t* __restrict__ QK,
                                               const bf16_t* __restrict__ VT,
                                               const float* __restrict__ amask,
                                               bf16_t* __restrict__ Att) {
  extern __shared__ char lds[];
  bf16_t* Ks = (bf16_t*)lds;
  bf16_t* Vs = (bf16_t*)(lds + 16384);
  float* bias = (float*)(lds + 32768);          // 3*128 f32 = 1536 B
  const int t = threadIdx.x, w = t >> 6, l = t & 63, lr = l & 15, lg = l >> 4;
  char* Psw = lds + 34304 + w * 4352;

  const int idx = (blockIdx.x & 7) * 256 + (blockIdx.x >> 3);
  const int n = idx & 31, h = (idx >> 5) & 15, b = idx >> 9;
  const long rowQ = (long)b * 4096 + n * 128;

  bf16x8 qf[2];
#pragma unroll
  for (int ks = 0; ks < 2; ++ks)
    qf[ks] = *(const bf16x8*)&QK[(rowQ + w * 16 + lr) * 2048 + h * 64 + ks * 32 + lg * 8];

  f32x4 oT[4] = {};
  float m_run = -1e30f, l_run = 0.f;

  const int kcLo = (n > 0) ? n - 1 : 0;
  const int kcHi = (n < 31) ? n + 1 : 31;
  const long kbase0 = (long)b * 4096 + (long)kcLo * 128;
  const int nch = kcHi - kcLo + 1;

  const int kcol = ((t & 7) ^ ((t >> 3) & 7)) * 8;
  const bf16_t* gK0 = QK + (kbase0 + (t >> 3)) * 2048 + 1024 + h * 64 + kcol;
  const int vrow = t >> 4;
  const int vcol = ((t & 15) ^ ((t >> 4) & 15)) * 8;
  const bf16_t* gV0 = VT + ((long)h * 64 + vrow) * 16384 + kbase0 + vcol;

  bf16_t* lK0 = Ks + t * 8;
  bf16_t* lK1 = Ks + 4096 + t * 8;
  bf16_t* lV0 = Vs + t * 8;
  bf16_t* lV1 = Vs + 4096 + t * 8;

#define STAGE_K(cc)                                               \
  {                                                               \
    const bf16_t* _k = gK0 + (long)(cc) * 128 * 2048;             \
    g2l16(_k, lK0);                                               \
    g2l16(_k + (long)64 * 2048, lK1);                             \
  }
#define STAGE_V(cc)                                               \
  {                                                               \
    const bf16_t* _v = gV0 + (long)(cc) * 128;                    \
    g2l16(_v, lV0);                                               \
    g2l16(_v + (long)32 * 16384, lV1);                            \
  }

  // prologue: stage chunk 0, preload bias for all chunks, single full drain
  STAGE_K(0); STAGE_V(0);
  if (t < nch * 32) {
    float4 mv = *(const float4*)(amask + kbase0 + t * 4);
    float4 bv;
    bv.x = mv.x > 0.f ? 0.f : -1e30f;
    bv.y = mv.y > 0.f ? 0.f : -1e30f;
    bv.z = mv.z > 0.f ? 0.f : -1e30f;
    bv.w = mv.w > 0.f ? 0.f : -1e30f;
    *(float4*)&bias[t * 4] = bv;
  }
  FENCE();
  asm volatile("s_waitcnt vmcnt(0)" ::: "memory");
  __syncthreads();

  for (int c = 0; c < nch; ++c) {
    const bool more = (c + 1) < nch;

    // ---- QK^T -> S^T (lane: q=lr, keys = kb*16 + lg*4 + r) ----
    f32x4 s[8];
#pragma unroll
    for (int kb = 0; kb < 8; ++kb) {
      f32x4 z = {};
#pragma unroll
      for (int ks = 0; ks < 2; ++ks) {
        bf16x8 kA = *(const bf16x8*)&Ks[(kb * 16 + lr) * 64 + (((ks * 4 + lg) ^ (lr & 7)) * 8)];
        z = mfma16(kA, qf[ks], z);
      }
      s[kb] = z;
    }
    FENCE();
    __builtin_amdgcn_s_barrier();   // all waves done reading Ks
    if (more) STAGE_K(c + 1);       // overwrite Ks; landing checked at loop end

    // ---- online softmax ----
    float mt = -3e30f;
#pragma unroll
    for (int kb = 0; kb < 8; ++kb) {
      f32x4 bb = *(const f32x4*)&bias[c * 128 + kb * 16 + lg * 4];
#pragma unroll
      for (int r = 0; r < 4; ++r) {
        float sv = s[kb][r] * 0.125f + bb[r];
        s[kb][r] = sv;
        mt = fmaxf(mt, sv);
      }
    }
    mt = fmaxf(mt, __shfl_xor(mt, 16));
    mt = fmaxf(mt, __shfl_xor(mt, 32));
    float mnew = fmaxf(m_run, mt);
    float alpha = __expf(m_run - mnew);
    m_run = mnew;
    float rs = 0.f;
#pragma unroll
    for (int kb = 0; kb < 8; ++kb)
#pragma unroll
      for (int r = 0; r < 4; ++r) {
        float p = __expf(s[kb][r] - mnew);
        s[kb][r] = p;
        rs += p;
      }
    rs += __shfl_xor(rs, 16);
    rs += __shfl_xor(rs, 32);
    l_run = l_run * alpha + rs;
#pragma unroll
    for (int df = 0; df < 4; ++df)
#pragma unroll
      for (int r = 0; r < 4; ++r) oT[df][r] *= alpha;

    // ---- P^T -> per-wave LDS (b64), wave-level fence before cross-lane reads ----
#pragma unroll
    for (int kb = 0; kb < 8; ++kb) {
      bf16x4 pv;
      pv[0] = (bf16_t)s[kb][0]; pv[1] = (bf16_t)s[kb][1];
      pv[2] = (bf16_t)s[kb][2]; pv[3] = (bf16_t)s[kb][3];
      *(bf16x4*)(Psw + lr * 272 + kb * 32 + lg * 8) = pv;
    }
    asm volatile("s_waitcnt lgkmcnt(0)" ::: "memory");
    __builtin_amdgcn_sched_barrier(0);

    // V(c) must be landed in all waves (outstanding after wait: K(c+1) only)
    FENCE();
    if (more) asm volatile("s_waitcnt vmcnt(2)" ::: "memory");
    else      asm volatile("s_waitcnt vmcnt(0)" ::: "memory");
    __builtin_amdgcn_s_barrier();

    // ---- PV: O^T[d,q] += V^T x P^T ----
#pragma unroll
    for (int ks = 0; ks < 4; ++ks) {
      bf16x8 pB = *(const bf16x8*)(Psw + lr * 272 + ks * 64 + lg * 16);
#pragma unroll
      for (int df = 0; df < 4; ++df) {
        bf16x8 vA = *(const bf16x8*)&Vs[(df * 16 + lr) * 128 + (((ks * 4 + lg) ^ lr) * 8)];
        oT[df] = mfma16(vA, pB, oT[df]);
      }
    }
    FENCE();
    __builtin_amdgcn_s_barrier();   // all waves done reading Vs
    if (more) {
      STAGE_V(c + 1);
      FENCE();
      asm volatile("s_waitcnt vmcnt(2)" ::: "memory");  // K(c+1) landed; V(c+1) in flight
      __builtin_amdgcn_s_barrier();
    }
  }
#undef STAGE_K
#undef STAGE_V

  // ---- epilogue: normalize, transpose O^T via per-wave Psw, coalesced store ----
  float inv = 1.f / l_run;
#pragma unroll
  for (int df = 0; df < 4; ++df) {
    bf16x4 ov;
#pragma unroll
    for (int r = 0; r < 4; ++r) ov[r] = (bf16_t)(oT[df][r] * inv);
    *(bf16x4*)(Psw + lr * 272 + df * 32 + lg * 8) = ov;
  }
  asm volatile("s_waitcnt lgkmcnt(0)" ::: "memory");
  __builtin_amdgcn_sched_barrier(0);
  const char* myP = lds + 34304 + w * 4352;
  bf16x8 r0 = *(const bf16x8*)(myP + (l >> 2) * 272 + (l & 3) * 32);
  bf16x8 r1 = *(const bf16x8*)(myP + (l >> 2) * 272 + (l & 3) * 32 + 16);
  long orow = rowQ + w * 16 + (l >> 2);
  bf16_t* op = Att + orow * 1024 + h * 64 + (l & 3) * 16;
  *(bf16x8*)op = r0;
  *(bf16x8*)(op + 8) = r1;
}

// ---------------- launch ----------------
extern "C" void kernel_launch(void* const* d_in, const int* in_sizes, int n_in,
                              void* d_out, int out_size, void* d_ws, size_t ws_size,
                              hipStream_t stream) {
  const float* x  = (const float*)d_in[0];
  const float* am = (const float*)d_in[1];
  const float* Wq = (const float*)d_in[2];
  const float* Wk = (const float*)d_in[3];
  const float* Wv = (const float*)d_in[4];
  const float* Wo = (const float*)d_in[5];
  float* out = (float*)d_out;

  char* ws = (char*)d_ws;
  bf16_t* qk  = (bf16_t*)ws;                        // [16384,2048] = 67108864 B
  bf16_t* vt  = (bf16_t*)(ws + 67108864);           // [1024,16384] = 33554432 B
  bf16_t* xbx = (bf16_t*)(ws + 100663296);          // [16384,1024] bf16 x; reused as attended
  bf16_t* wqk = (bf16_t*)(ws + 134217728);          // [2048,1024] rows: Wq, Wk
  bf16_t* wvb = (bf16_t*)(ws + 138412032);          // [1024,1024] Wv
  bf16_t* wob = (bf16_t*)(ws + 140509184);          // [1024,1024] Wo

  const int kSmemG = 131072;
  hipFuncSetAttribute(reinterpret_cast<const void*>(&gemm256<bf16_t>),
                      hipFuncAttributeMaxDynamicSharedMemorySize, kSmemG);
  hipFuncSetAttribute(reinterpret_cast<const void*>(&gemm256<float>),
                      hipFuncAttributeMaxDynamicSharedMemorySize, kSmemG);
  const int kSmemS = 69120;  // Ks 16K + Vs 16K + bias 1.5K + Psw 8*4352
  hipFuncSetAttribute(reinterpret_cast<const void*>(&swa3),
                      hipFuncAttributeMaxDynamicSharedMemorySize, kSmemS);

  cvt_f32_bf16<<<8192, 256, 0, stream>>>(x, xbx);
  cvt_f32_bf16<<<512, 256, 0, stream>>>(Wq, wqk);
  cvt_f32_bf16<<<512, 256, 0, stream>>>(Wk, wqk + 1048576);
  cvt_f32_bf16<<<512, 256, 0, stream>>>(Wv, wvb);
  cvt_f32_bf16<<<512, 256, 0, stream>>>(Wo, wob);

  // QK projection: [16384,1024] x [2048,1024]^T -> qk [16384,2048]
  gemm256<bf16_t><<<512, 512, kSmemG, stream>>>(xbx, wqk, qk, 16384, 2048, 1024, 8);

  // V^T projection: Vt = Wv * x^T : A=[1024,1024], Bt=[16384,1024] -> vt [1024,16384]
  gemm256<bf16_t><<<256, 512, kSmemG, stream>>>(wvb, xbx, vt, 1024, 16384, 1024, 64);

  // local attention -> attended [16384,1024] bf16 (overwrites xbx)
  swa3<<<2048, 512, kSmemS, stream>>>(qk, vt, am, xbx);

  // output projection: [16384,1024] x [1024,1024]^T -> d_out f32
  gemm256<float><<<256, 512, kSmemG, stream>>>(xbx, wob, out, 16384, 1024, 1024, 4);
}